// Round 15
// baseline (167.504 us; speedup 1.0000x reference)
//
#include <hip/hip_runtime.h>
#include <hip/hip_fp16.h>

// ---------------------------------------------------------------------------
// 2-layer GCN on MI355X.
//   GCNConv(x) = A_hat (x W) + b = (A_hat x) W + b, and emb[labels]@W1 =
//   (emb@W1)[labels] -> layer 1 gathers from a 128KB fp8 L2-resident table;
//   layer 2 aggregates first, then in-place GEMM on d_out.
// CSR build (zero global atomics): K1 hist (+fused fp8 temb) / K2 colscan /
// K2b ebase / K3 scatter / K4 bsort (+dinv fold) / repack.
// repack emits PACKED 4B edge records: csrA = label<<16|h(w*dinv[src]) for
// agg1, csrB = src<<16|h(w*dinv[src]) for agg2 -> aggs do one 4B batch load,
// ONE shfl per edge-pair (addr+weight in one word), no dinv gather.
// Both gather tables fp8 E4M3 x64-prescaled (rows 128B): R14 proved byte
// shrink is the lever for agg2 (beyond-L2 fabric-bound); fp8 also halves
// agg1's decode cvts (cvt_pk_f32_fp8 yields 2 floats/op).
// Aggs: pair-gather, batch-64, shfl-broadcast pairs, next-batch prefetch,
// 32-bit byte-offset gathers. (R9/R11 lessons: keep register pair-gather +
// high occupancy; no LDS staging, no feature chunking.)
// ---------------------------------------------------------------------------

#define CHUNKS 256  // chunk = ceil(e/256) = 6250 for e=1.6M
#define BSTAGE 2816 // bucket stage entries (avg bucket = 2048)

typedef float floatx2 __attribute__((ext_vector_type(2)));

// K1: blocks [0,bact): per-chunk histogram of dst-buckets.
//     blocks [bact, ...): temb8 = fp8(64 * emb @ W1), 32 rows/block,
//     lane owns 4 features -> packed uint store.
__global__ __launch_bounds__(1024) void hist_temb_kernel(
    const int* __restrict__ dst, int* __restrict__ hist, int e, int chunk,
    int nb, int bact, const float* __restrict__ emb,
    const float* __restrict__ W1, unsigned* __restrict__ temb8, int vocab) {
  __shared__ unsigned lh[1024];
  __shared__ float xs[32][128];
  int b = blockIdx.x, t = threadIdx.x;
  if (b < bact) {
    lh[t] = 0;
    __syncthreads();
    int start = b * chunk, end = min(e, start + chunk);
    for (int i = start + t; i < end; i += 1024) atomicAdd(&lh[dst[i] >> 6], 1u);
    __syncthreads();
    if (t < nb) hist[(size_t)t * CHUNKS + b] = (int)lh[t];
  } else {
    int row = t >> 5, fl = t & 31;
    int r = (b - bact) * 32 + row;
    if (r < vocab)
      *(float4*)&xs[row][fl * 4] = *(const float4*)(emb + (size_t)r * 128 + fl * 4);
    __syncthreads();
    if (r < vocab) {
      float a0 = 0.f, a1 = 0.f, a2 = 0.f, a3 = 0.f;
#pragma unroll 4
      for (int k = 0; k < 128; ++k) {
        float xv = xs[row][k];
        float4 w4 = *(const float4*)(W1 + k * 128 + fl * 4);
        a0 = fmaf(xv, w4.x, a0); a1 = fmaf(xv, w4.y, a1);
        a2 = fmaf(xv, w4.z, a2); a3 = fmaf(xv, w4.w, a3);
      }
      int pk = __builtin_amdgcn_cvt_pk_fp8_f32(a0 * 64.f, a1 * 64.f, 0, false);
      pk = __builtin_amdgcn_cvt_pk_fp8_f32(a2 * 64.f, a3 * 64.f, pk, true);
      temb8[(size_t)r * 32 + fl] = (unsigned)pk;
    }
  }
}

// K2: one wave per bucket k: exclusive scan of hist[k][*] over chunks.
__global__ __launch_bounds__(256) void colscan_kernel(const int* __restrict__ hist,
                                                      int* __restrict__ off,
                                                      int* __restrict__ tot,
                                                      int nb, int bact) {
  int k = (blockIdx.x * 256 + threadIdx.x) >> 6;
  int lane = threadIdx.x & 63;
  if (k >= nb) return;
  int carry = 0;
  for (int r = 0; r < CHUNKS / 64; ++r) {
    int b = r * 64 + lane;
    int h = (b < bact) ? hist[(size_t)k * CHUNKS + b] : 0;
    int x = h;
#pragma unroll
    for (int d = 1; d < 64; d <<= 1) {
      int tt = __shfl_up(x, d, 64);
      if (lane >= d) x += tt;
    }
    if (b < bact) off[(size_t)k * CHUNKS + b] = carry + x - h;
    carry += __shfl(x, 63, 64);
  }
  if (lane == 0) tot[k] = carry;
}

// K2b: single block: exclusive scan of tot[nb] -> ebase[nb+1].
__global__ __launch_bounds__(1024) void ebase_kernel(const int* __restrict__ tot,
                                                     int* __restrict__ ebase, int nb) {
  __shared__ int wsum[16];
  int t = threadIdx.x, lane = t & 63, wv = t >> 6;
  int v = (t < nb) ? tot[t] : 0;
  int x = v;
#pragma unroll
  for (int d = 1; d < 64; d <<= 1) {
    int tt = __shfl_up(x, d, 64);
    if (lane >= d) x += tt;
  }
  if (lane == 63) wsum[wv] = x;
  __syncthreads();
  int o = 0;
#pragma unroll
  for (int w = 0; w < 16; ++w) o += (w < wv) ? wsum[w] : 0;
  int excl = x - v + o;
  if (t < nb) ebase[t] = excl;
  if (t == nb - 1) ebase[nb] = excl + v;
}

// K3: scatter edges into bucket-grouped records (LDS rank, no global atomics).
__global__ __launch_bounds__(1024) void scatter_kernel(
    const int* __restrict__ src, const int* __restrict__ dst,
    const float* __restrict__ w, const int* __restrict__ labels,
    const int* __restrict__ off, const int* __restrict__ ebase,
    int2* __restrict__ brec, int e, int chunk, int nb) {
  __shared__ unsigned bincnt[1024];
  __shared__ int gbase[1024];
  int b = blockIdx.x, t = threadIdx.x;
  bincnt[t] = 0;
  if (t < nb) gbase[t] = ebase[t] + off[(size_t)t * CHUNKS + b];
  __syncthreads();
  int start = b * chunk, end = min(e, start + chunk);
  int s[7], d[7], lb[7], ps[7];
  float wv[7];
#pragma unroll
  for (int u = 0; u < 7; ++u) {
    int i = start + u * 1024 + t;
    bool ok = i < end;
    s[u] = ok ? src[i] : 0;
    d[u] = ok ? dst[i] : 0;
    wv[u] = ok ? w[i] : 0.f;
  }
#pragma unroll
  for (int u = 0; u < 7; ++u) lb[u] = labels[s[u]];
#pragma unroll
  for (int u = 0; u < 7; ++u) ps[u] = gbase[d[u] >> 6];
#pragma unroll
  for (int u = 0; u < 7; ++u) {
    int i = start + u * 1024 + t;
    if (i < end) {
      int k = d[u] >> 6;
      unsigned lr = atomicAdd(&bincnt[k], 1u);
      unsigned rx = (unsigned)s[u] | ((unsigned)(d[u] & 63) << 16) |
                    ((unsigned)lb[u] << 22);
      brec[ps[u] + (int)lr] = make_int2((int)rx, __float_as_int(wv[u]));
    }
  }
}

// K4: per-bucket 64-bin sort: brec -> csr (src|label<<16, w), + rs[] + dinv.
// 2-way split histograms/cursors halve same-address LDS atomic serialization.
__global__ __launch_bounds__(256) void bsort_kernel(const int2* __restrict__ brec,
                                                    const int* __restrict__ ebase,
                                                    int2* __restrict__ csr,
                                                    int* __restrict__ rs,
                                                    float* __restrict__ dinv, int n) {
  __shared__ int2 stage[BSTAGE];
  __shared__ unsigned h64[2][64];
  __shared__ unsigned cur[2][64];
  __shared__ float rsum[2][64];
  int k = blockIdx.x, t = threadIdx.x;
  int p = t >> 7;
  int e0 = ebase[k], e1 = ebase[k + 1], cnt = e1 - e0;
  if (t < 128) { h64[t >> 6][t & 63] = 0; rsum[t >> 6][t & 63] = 0.f; }
  __syncthreads();
  bool fits = (cnt <= BSTAGE);
  for (int i = t; i < cnt; i += 256) {
    int2 r = brec[e0 + i];
    if (fits) stage[i] = r;
    unsigned dl = ((unsigned)r.x >> 16) & 63u;
    atomicAdd(&h64[p][dl], 1u);
    atomicAdd(&rsum[p][dl], __int_as_float(r.y));
  }
  __syncthreads();
  if (t < 64) {
    int h0 = (int)h64[0][t];
    int hv = h0 + (int)h64[1][t];
    int x = hv;
#pragma unroll
    for (int d = 1; d < 64; d <<= 1) {
      int tt = __shfl_up(x, d, 64);
      if (t >= d) x += tt;
    }
    int ex = x - hv;
    cur[0][t] = (unsigned)(e0 + ex);
    cur[1][t] = (unsigned)(e0 + ex + h0);
    int v = k * 64 + t;
    if (v <= n) rs[v] = e0 + ex;
    if (v < n) dinv[v] = rsqrtf(1.0f + rsum[0][t] + rsum[1][t]);
  }
  __syncthreads();
  for (int i = t; i < cnt; i += 256) {
    int2 r = fits ? stage[i] : brec[e0 + i];
    unsigned rx = (unsigned)r.x;
    int dl = (int)((rx >> 16) & 63u);
    int pos = (int)atomicAdd(&cur[p][dl], 1u);
    csr[pos] = make_int2((int)((rx & 0xffffu) | ((rx >> 22) << 16)), r.y);
  }
}

// repack: csr {src|label<<16, w} -> csrA = label<<16|h(w'), csrB = src<<16|
// h(w'), where w' = w * dinv[src] (fp16). One 4B record per agg per edge.
__global__ __launch_bounds__(256) void repack_kernel(const int2* __restrict__ csr,
                                                     const float* __restrict__ dinv,
                                                     unsigned* __restrict__ csrA,
                                                     unsigned* __restrict__ csrB,
                                                     int e) {
  int i = blockIdx.x * 1024 + threadIdx.x;
  int2 c[4];
  float wp[4];
#pragma unroll
  for (int u = 0; u < 4; ++u) {
    int k = i + u * 256;
    c[u] = (k < e) ? csr[k] : make_int2(0, 0);
  }
#pragma unroll
  for (int u = 0; u < 4; ++u)
    wp[u] = __int_as_float(c[u].y) * dinv[c[u].x & 0xffff];
#pragma unroll
  for (int u = 0; u < 4; ++u) {
    int k = i + u * 256;
    if (k < e) {
      unsigned hb = (unsigned)__half_as_ushort(__float2half_rn(wp[u]));
      csrA[k] = ((((unsigned)c[u].x) >> 16) << 16) | hb;
      csrB[k] = (((unsigned)c[u].x) << 16) | hb;
    }
  }
}

// Layer 1: out8 = fp8(64*relu(A_hat temb[labels] + b1)); temb8 fp8 (x64),
// csrA packed records. Pair-gather, one shfl per pair-iter, prefetch.
__global__ __launch_bounds__(256) void agg1_kernel(
    const int* __restrict__ rs, const unsigned* __restrict__ csrA,
    const float* __restrict__ dinv, const int* __restrict__ labels,
    const unsigned* __restrict__ temb8, const float* __restrict__ b1,
    unsigned* __restrict__ out8, int n) {
  int wid = (blockIdx.x * blockDim.x + threadIdx.x) >> 6;
  int lane = threadIdx.x & 63;
  if (wid >= n) return;
  int half = lane >> 5, fl = lane & 31;
  unsigned flo = (unsigned)(fl << 2);
  const char* tb = (const char*)temb8;
  float di = dinv[wid];
  float acc0, acc1, acc2, acc3;
  {
    unsigned r8 = *(const unsigned*)(tb + (((unsigned)labels[wid]) << 7) + flo);
    floatx2 a = __builtin_amdgcn_cvt_pk_f32_fp8((int)r8, false);
    floatx2 b = __builtin_amdgcn_cvt_pk_f32_fp8((int)r8, true);
    float ss = half ? 0.f : di;  // self term once (half 0 only)
    acc0 = a[0] * ss; acc1 = a[1] * ss; acc2 = b[0] * ss; acc3 = b[1] * ss;
  }
  int base0 = rs[wid], r1v = rs[wid + 1];
  unsigned x = 0;  // packed record; 0 -> w=0 contributes nothing
  if (base0 + lane < r1v) x = csrA[base0 + lane];
  for (int base = base0; base < r1v; base += 64) {
    unsigned nx = 0;
    if (base + 64 + lane < r1v) nx = csrA[base + 64 + lane];
    int nb = min(64, r1v - base);
    int j = 0;
    for (; j + 16 <= nb; j += 16) {
#pragma unroll
      for (int u = 0; u < 8; ++u) {
        unsigned xj = (unsigned)__shfl((int)x, j + 2 * u + half, 64);
        float vj = __half2float(__ushort_as_half((unsigned short)(xj & 0xffffu)));
        unsigned r8 = *(const unsigned*)(tb + ((xj >> 16) << 7) + flo);
        floatx2 a = __builtin_amdgcn_cvt_pk_f32_fp8((int)r8, false);
        floatx2 b = __builtin_amdgcn_cvt_pk_f32_fp8((int)r8, true);
        acc0 = fmaf(a[0], vj, acc0); acc1 = fmaf(a[1], vj, acc1);
        acc2 = fmaf(b[0], vj, acc2); acc3 = fmaf(b[1], vj, acc3);
      }
    }
    for (; j + 2 <= nb; j += 2) {
      unsigned xj = (unsigned)__shfl((int)x, j + half, 64);
      float vj = __half2float(__ushort_as_half((unsigned short)(xj & 0xffffu)));
      unsigned r8 = *(const unsigned*)(tb + ((xj >> 16) << 7) + flo);
      floatx2 a = __builtin_amdgcn_cvt_pk_f32_fp8((int)r8, false);
      floatx2 b = __builtin_amdgcn_cvt_pk_f32_fp8((int)r8, true);
      acc0 = fmaf(a[0], vj, acc0); acc1 = fmaf(a[1], vj, acc1);
      acc2 = fmaf(b[0], vj, acc2); acc3 = fmaf(b[1], vj, acc3);
    }
    if (j < nb) {  // leftover single edge: half 1 contributes 0
      unsigned xj = (unsigned)__shfl((int)x, j, 64);
      float vj0 = __half2float(__ushort_as_half((unsigned short)(xj & 0xffffu)));
      float vj = half ? 0.f : vj0;
      unsigned r8 = *(const unsigned*)(tb + ((xj >> 16) << 7) + flo);
      floatx2 a = __builtin_amdgcn_cvt_pk_f32_fp8((int)r8, false);
      floatx2 b = __builtin_amdgcn_cvt_pk_f32_fp8((int)r8, true);
      acc0 = fmaf(a[0], vj, acc0); acc1 = fmaf(a[1], vj, acc1);
      acc2 = fmaf(b[0], vj, acc2); acc3 = fmaf(b[1], vj, acc3);
    }
    x = nx;
  }
  acc0 += __shfl_xor(acc0, 32, 64);
  acc1 += __shfl_xor(acc1, 32, 64);
  acc2 += __shfl_xor(acc2, 32, 64);
  acc3 += __shfl_xor(acc3, 32, 64);
  if (half == 0) {
    float4 b4 = ((const float4*)b1)[fl];
    // temb8 is 64x true scale: relu(acc*di + 64*b) = 64*relu(true) directly
    acc0 = fmaxf(fmaf(acc0, di, b4.x * 64.f), 0.f);
    acc1 = fmaxf(fmaf(acc1, di, b4.y * 64.f), 0.f);
    acc2 = fmaxf(fmaf(acc2, di, b4.z * 64.f), 0.f);
    acc3 = fmaxf(fmaf(acc3, di, b4.w * 64.f), 0.f);
    int pk = __builtin_amdgcn_cvt_pk_fp8_f32(acc0, acc1, 0, false);
    pk = __builtin_amdgcn_cvt_pk_fp8_f32(acc2, acc3, pk, true);
    out8[(size_t)wid * 32 + fl] = (unsigned)pk;
  }
}

// Layer 2 aggregation: out = A_hat h (fp8 source, f32 out); csrB packed.
__global__ __launch_bounds__(256) void agg2_kernel(
    const int* __restrict__ rs, const unsigned* __restrict__ csrB,
    const float* __restrict__ dinv, const unsigned* __restrict__ h8,
    float* __restrict__ out, int n) {
  int wid = (blockIdx.x * blockDim.x + threadIdx.x) >> 6;
  int lane = threadIdx.x & 63;
  if (wid >= n) return;
  int half = lane >> 5, fl = lane & 31;
  unsigned flo = (unsigned)(fl << 2);
  const char* hb = (const char*)h8;
  float di = dinv[wid];
  float acc0, acc1, acc2, acc3;
  {
    unsigned r8 = *(const unsigned*)(hb + (((unsigned)wid) << 7) + flo);
    floatx2 a = __builtin_amdgcn_cvt_pk_f32_fp8((int)r8, false);
    floatx2 b = __builtin_amdgcn_cvt_pk_f32_fp8((int)r8, true);
    float ss = half ? 0.f : di;
    acc0 = a[0] * ss; acc1 = a[1] * ss; acc2 = b[0] * ss; acc3 = b[1] * ss;
  }
  int base0 = rs[wid], r1v = rs[wid + 1];
  unsigned x = 0;
  if (base0 + lane < r1v) x = csrB[base0 + lane];
  for (int base = base0; base < r1v; base += 64) {
    unsigned nx = 0;
    if (base + 64 + lane < r1v) nx = csrB[base + 64 + lane];
    int nb = min(64, r1v - base);
    int j = 0;
    for (; j + 16 <= nb; j += 16) {
#pragma unroll
      for (int u = 0; u < 8; ++u) {
        unsigned xj = (unsigned)__shfl((int)x, j + 2 * u + half, 64);
        float vj = __half2float(__ushort_as_half((unsigned short)(xj & 0xffffu)));
        unsigned r8 = *(const unsigned*)(hb + ((xj >> 16) << 7) + flo);
        floatx2 a = __builtin_amdgcn_cvt_pk_f32_fp8((int)r8, false);
        floatx2 b = __builtin_amdgcn_cvt_pk_f32_fp8((int)r8, true);
        acc0 = fmaf(a[0], vj, acc0); acc1 = fmaf(a[1], vj, acc1);
        acc2 = fmaf(b[0], vj, acc2); acc3 = fmaf(b[1], vj, acc3);
      }
    }
    for (; j + 2 <= nb; j += 2) {
      unsigned xj = (unsigned)__shfl((int)x, j + half, 64);
      float vj = __half2float(__ushort_as_half((unsigned short)(xj & 0xffffu)));
      unsigned r8 = *(const unsigned*)(hb + ((xj >> 16) << 7) + flo);
      floatx2 a = __builtin_amdgcn_cvt_pk_f32_fp8((int)r8, false);
      floatx2 b = __builtin_amdgcn_cvt_pk_f32_fp8((int)r8, true);
      acc0 = fmaf(a[0], vj, acc0); acc1 = fmaf(a[1], vj, acc1);
      acc2 = fmaf(b[0], vj, acc2); acc3 = fmaf(b[1], vj, acc3);
    }
    if (j < nb) {
      unsigned xj = (unsigned)__shfl((int)x, j, 64);
      float vj0 = __half2float(__ushort_as_half((unsigned short)(xj & 0xffffu)));
      float vj = half ? 0.f : vj0;
      unsigned r8 = *(const unsigned*)(hb + ((xj >> 16) << 7) + flo);
      floatx2 a = __builtin_amdgcn_cvt_pk_f32_fp8((int)r8, false);
      floatx2 b = __builtin_amdgcn_cvt_pk_f32_fp8((int)r8, true);
      acc0 = fmaf(a[0], vj, acc0); acc1 = fmaf(a[1], vj, acc1);
      acc2 = fmaf(b[0], vj, acc2); acc3 = fmaf(b[1], vj, acc3);
    }
    x = nx;
  }
  acc0 += __shfl_xor(acc0, 32, 64);
  acc1 += __shfl_xor(acc1, 32, 64);
  acc2 += __shfl_xor(acc2, 32, 64);
  acc3 += __shfl_xor(acc3, 32, 64);
  if (half == 0) {
    float sc = di * 0.015625f;  // /64 de-scale
    ((float4*)(out + (size_t)wid * 128))[fl] =
        make_float4(acc0 * sc, acc1 * sc, acc2 * sc, acc3 * sc);
  }
}

// In-place: y[rb..rb+31] = y[rb..rb+31] @ W + b.
__global__ __launch_bounds__(256) void gemm_bias_kernel(float* __restrict__ y,
                                                        const float* __restrict__ W,
                                                        const float* __restrict__ bias,
                                                        int n) {
  __shared__ float xs[32][128];
  int tid = threadIdx.x;
  int tc = tid & 31;
  int tr = tid >> 5;
  int rb = blockIdx.x * 32;
  {
    const float4* xg = (const float4*)(y + (size_t)rb * 128);
    float4* xls = (float4*)&xs[0][0];
#pragma unroll
    for (int i = 0; i < 4; ++i) {
      int idx = tid + i * 256;
      int row = rb + (idx >> 5);
      float4 val = (row < n) ? xg[idx] : make_float4(0.f, 0.f, 0.f, 0.f);
      xls[idx] = val;
    }
  }
  __syncthreads();
  int j0 = tc * 4;
  float4 b4 = *(const float4*)(bias + j0);
  float acc[4][4];
#pragma unroll
  for (int r = 0; r < 4; ++r) {
    acc[r][0] = b4.x; acc[r][1] = b4.y; acc[r][2] = b4.z; acc[r][3] = b4.w;
  }
#pragma unroll 4
  for (int k = 0; k < 128; ++k) {
    float4 w4 = *(const float4*)(W + k * 128 + j0);
#pragma unroll
    for (int r = 0; r < 4; ++r) {
      float xv = xs[tr * 4 + r][k];
      acc[r][0] = fmaf(xv, w4.x, acc[r][0]);
      acc[r][1] = fmaf(xv, w4.y, acc[r][1]);
      acc[r][2] = fmaf(xv, w4.z, acc[r][2]);
      acc[r][3] = fmaf(xv, w4.w, acc[r][3]);
    }
  }
#pragma unroll
  for (int r = 0; r < 4; ++r) {
    int row = rb + tr * 4 + r;
    if (row < n)
      *(float4*)(y + (size_t)row * 128 + j0) =
          make_float4(acc[r][0], acc[r][1], acc[r][2], acc[r][3]);
  }
}

extern "C" void kernel_launch(void* const* d_in, const int* in_sizes, int n_in,
                              void* d_out, int out_size, void* d_ws, size_t ws_size,
                              hipStream_t stream) {
  const int* labels = (const int*)d_in[0];
  const int* edge_index = (const int*)d_in[1];
  const float* weight = (const float*)d_in[2];
  const float* emb = (const float*)d_in[3];
  const float* W1 = (const float*)d_in[4];
  const float* b1 = (const float*)d_in[5];
  const float* W2 = (const float*)d_in[6];
  const float* b2 = (const float*)d_in[7];

  int n = in_sizes[0];
  int e = in_sizes[1] / 2;
  int vocab = in_sizes[3] / 128;
  const int* srcp = edge_index;
  const int* dstp = edge_index + e;

  int nb = (n + 63) >> 6;                 // dst buckets (782)
  int chunk = (e + CHUNKS - 1) / CHUNKS;  // 6250
  int bact = (e + chunk - 1) / chunk;
  int tblocks = (vocab + 31) / 32;        // temb blocks (32)

  float* ws = (float*)d_ws;
  size_t o = 0;
  auto alloc_f = [&](size_t c) { float* p = ws + o; o += (c + 255) & ~(size_t)255; return p; };
  int*      hist  = (int*)alloc_f((size_t)nb * CHUNKS);
  int*      off   = (int*)alloc_f((size_t)nb * CHUNKS);
  int*      tot   = (int*)alloc_f(nb);
  int*      ebase = (int*)alloc_f(nb + 1);
  int2*     brec  = (int2*)alloc_f((size_t)e * 2);
  int*      rs    = (int*)alloc_f(n + 1);
  int2*     csr   = (int2*)alloc_f((size_t)e * 2);
  unsigned* csrA  = (unsigned*)alloc_f(e);
  unsigned* csrB  = (unsigned*)alloc_f(e);
  float*    dinv  = alloc_f(n);
  unsigned* temb8 = (unsigned*)alloc_f((size_t)vocab * 32);  // vocab*128 fp8
  unsigned* out8  = (unsigned*)alloc_f((size_t)n * 32);      // n*128 fp8
  (void)ws_size;

  dim3 b256(256);
  dim3 b1024(1024);
  int gagg = (int)(((size_t)n * 64 + 255) / 256);

  hist_temb_kernel<<<bact + tblocks, b1024, 0, stream>>>(dstp, hist, e, chunk, nb,
                                                         bact, emb, W1, temb8, vocab);
  colscan_kernel<<<(nb * 64 + 255) / 256, b256, 0, stream>>>(hist, off, tot, nb, bact);
  ebase_kernel<<<1, b1024, 0, stream>>>(tot, ebase, nb);
  scatter_kernel<<<bact, b1024, 0, stream>>>(srcp, dstp, weight, labels, off, ebase,
                                             brec, e, chunk, nb);
  bsort_kernel<<<nb, b256, 0, stream>>>(brec, ebase, csr, rs, dinv, n);
  repack_kernel<<<(e + 1023) / 1024, b256, 0, stream>>>(csr, dinv, csrA, csrB, e);
  // layer 1: out8 = fp8(64*relu(A_hat temb[labels] + b1))
  agg1_kernel<<<gagg, b256, 0, stream>>>(rs, csrA, dinv, labels, temb8, b1, out8, n);
  // layer 2: d_out = (A_hat out1) @ W2 + b2   (agg first, then in-place GEMM)
  agg2_kernel<<<gagg, b256, 0, stream>>>(rs, csrB, dinv, out8, (float*)d_out, n);
  gemm_bias_kernel<<<(n + 31) / 32, b256, 0, stream>>>((float*)d_out, W2, b2, n);
}